// Round 1
// baseline (104.728 us; speedup 1.0000x reference)
//
#include <hip/hip_runtime.h>
#include <hip/hip_bf16.h>
#include <math.h>

// Problem constants (from setup_inputs)
#define NB    192   // batch
#define NC    32    // feat channels
#define TFUT  27
#define HDIM  32

// ---------------------------------------------------------------------------
// Kernel 1: per-batch static features
//   pooled[2048] = 8x8 maxpool of feat_map[b]  (C*8*8)
//   past_enc[32] = traj_past[b] @ past_W.T + past_b
//   sta1[b][64]  = b1 + W1[:, 32:2112] @ [pooled, past_enc]
// ---------------------------------------------------------------------------
__global__ __launch_bounds__(1024) void k_static(
    const float* __restrict__ feat,      // (192,32,64,64)
    const float* __restrict__ traj_past, // (192,3,2)
    const float* __restrict__ past_W,    // (32,6)
    const float* __restrict__ past_b,    // (32)
    const float* __restrict__ W1,        // (64,2112)
    const float* __restrict__ b1,        // (64)
    float* __restrict__ sta1)            // (192,64)
{
    __shared__ __align__(16) float sta[2080];
    const int b = blockIdx.x;
    const int t = threadIdx.x;

    // Phase 1: maxpool. 1024 threads = 16 channels x 64 cells per iter, 2 iters.
    for (int it = 0; it < 2; ++it) {
        const int c    = it * 16 + (t >> 6);
        const int cell = t & 63;
        const int zi = cell >> 3, xi = cell & 7;
        const float* p = feat + ((size_t)b * NC + c) * 4096 + zi * 8 * 64 + xi * 8;
        float m = -3.402823466e38f;
        #pragma unroll
        for (int dz = 0; dz < 8; ++dz) {
            const float4 v0 = *reinterpret_cast<const float4*>(p + dz * 64);
            const float4 v1 = *reinterpret_cast<const float4*>(p + dz * 64 + 4);
            m = fmaxf(m, fmaxf(fmaxf(fmaxf(v0.x, v0.y), fmaxf(v0.z, v0.w)),
                               fmaxf(fmaxf(v1.x, v1.y), fmaxf(v1.z, v1.w))));
        }
        sta[c * 64 + cell] = m;
    }
    // Phase 2: past encoder
    if (t < 32) {
        float acc = past_b[t];
        #pragma unroll
        for (int k = 0; k < 6; ++k) acc += past_W[t * 6 + k] * traj_past[b * 6 + k];
        sta[2048 + t] = acc;
    }
    __syncthreads();

    // Phase 3: sta1[o] = b1[o] + sum_k W1[o][32+k]*sta[k]
    // 16 lanes per output o, contiguous float4 reads of W1 row.
    const int o = t >> 4, l = t & 15;
    const float* wrow = W1 + (size_t)o * 2112 + 32;
    float acc = 0.f;
    #pragma unroll 4
    for (int j = 0; j < 32; ++j) {
        const int k = j * 64 + l * 4;
        const float4 w = *reinterpret_cast<const float4*>(wrow + k);
        const float4 s = *reinterpret_cast<const float4*>(&sta[k]);
        acc += w.x * s.x + w.y * s.y + w.z * s.z + w.w * s.w;
    }
    if (l < 8) {  // remainder cols 2080..2111 (k = 2048..2079)
        const int k = 2048 + l * 4;
        const float4 w = *reinterpret_cast<const float4*>(wrow + k);
        const float4 s = *reinterpret_cast<const float4*>(&sta[k]);
        acc += w.x * s.x + w.y * s.y + w.z * s.z + w.w * s.w;
    }
    acc += __shfl_xor(acc, 1);
    acc += __shfl_xor(acc, 2);
    acc += __shfl_xor(acc, 4);
    acc += __shfl_xor(acc, 8);
    if (l == 0) sta1[b * 64 + o] = b1[o] + acc;
}

// ---------------------------------------------------------------------------
// Kernel 2: recurrent loop, one wave (64 threads) per batch element.
// All weights transposed into LDS so lane reads are consecutive (bank-free).
// ---------------------------------------------------------------------------
__global__ __launch_bounds__(64) void k_recur(
    const float* __restrict__ pred_map,  // (192,1,64,64)
    const float* __restrict__ noise,     // (192,27,2)
    const float* __restrict__ traj_past, // (192,3,2)
    const float* __restrict__ W_ih,      // (96,9)
    const float* __restrict__ W_hh,      // (96,32)
    const float* __restrict__ b_ih,      // (96)
    const float* __restrict__ b_hh,      // (96)
    const float* __restrict__ W1,        // (64,2112), cols 0..31 used
    const float* __restrict__ W2,        // (32,64)
    const float* __restrict__ b2,        // (32)
    const float* __restrict__ W3,        // (6,32)
    const float* __restrict__ b3,        // (6)
    const float* __restrict__ sta1g,     // (192,64)
    float* __restrict__ out)             // (192,27,2)
{
    __shared__ __align__(16) float pm[4096];
    __shared__ float WihT[9 * 96];
    __shared__ float WhhT[32 * 96];
    __shared__ float W1aT[32 * 64];
    __shared__ float W2T[64 * 32];
    __shared__ float W3s[6 * 32];
    __shared__ float bih[96], bhh[96], b2s[32], b3s[6];
    __shared__ float sta1[64];
    __shared__ float hx[32], win[6], dyn[9];
    __shared__ float gsum[64], gin[32], ghn[32];
    __shared__ float h1[64], h2[32], predv[6];

    const int b = blockIdx.x;
    const int l = threadIdx.x;

    // ---- stage weights / state into LDS ----
    {
        const float4* src = reinterpret_cast<const float4*>(pred_map + (size_t)b * 4096);
        float4* dst = reinterpret_cast<float4*>(pm);
        for (int i = l; i < 1024; i += 64) dst[i] = src[i];
    }
    for (int i = l; i < 9 * 96; i += 64)  { int o = i / 9,  k = i % 9;  WihT[k * 96 + o] = W_ih[i]; }
    for (int i = l; i < 32 * 96; i += 64) { int o = i >> 5, k = i & 31; WhhT[k * 96 + o] = W_hh[i]; }
    for (int i = l; i < 64 * 32; i += 64) { int o = i >> 5, k = i & 31; W1aT[k * 64 + o] = W1[(size_t)o * 2112 + k]; }
    for (int i = l; i < 32 * 64; i += 64) { int o = i >> 6, k = i & 63; W2T[k * 32 + o] = W2[i]; }
    for (int i = l; i < 6 * 32; i += 64)  W3s[i] = W3[i];
    for (int i = l; i < 96; i += 64)      { bih[i] = b_ih[i]; bhh[i] = b_hh[i]; }
    if (l < 32) b2s[l] = b2[l];
    if (l < 6)  b3s[l] = b3[l];
    sta1[l] = sta1g[b * 64 + l];
    if (l < 32) hx[l] = 0.f;
    if (l < 6)  win[l] = traj_past[b * 6 + l];
    __syncthreads();

    for (int ts = 0; ts < TFUT; ++ts) {
        // ---- Stage A: bilinear sample 3 window points from pred_map ----
        if (l < 3) {
            const float px = win[l * 2 + 0], pz = win[l * 2 + 1];
            // ref2mem: (v - MIN)/((MAX-MIN)/S) - 0.5 ; (32/64)=0.5 -> *2 exact
            float x = (px + 16.0f) * 2.0f - 0.5f;
            float z = (pz + 16.0f) * 2.0f - 0.5f;
            x = fminf(fmaxf(x, 0.0f), 63.0f);
            z = fminf(fmaxf(z, 0.0f), 63.0f);
            const float xf = floorf(x), zf = floorf(z);
            const int x0 = (int)xf, z0 = (int)zf;
            const int x1 = min(x0 + 1, 63), z1 = min(z0 + 1, 63);
            const float wx = x - xf, wz = z - zf;
            const float v00 = pm[z0 * 64 + x0], v01 = pm[z0 * 64 + x1];
            const float v10 = pm[z1 * 64 + x0], v11 = pm[z1 * 64 + x1];
            dyn[l] = v00 * (1.f - wx) * (1.f - wz) + v01 * wx * (1.f - wz)
                   + v10 * (1.f - wx) * wz        + v11 * wx * wz;
        }
        if (l < 6) dyn[3 + l] = win[l];
        __syncthreads();

        // ---- Stage B: GRU gates. lane l -> outputs l (and 64+l for l<32) ----
        float gi = bih[l];
        #pragma unroll
        for (int k = 0; k < 9; ++k) gi += WihT[k * 96 + l] * dyn[k];
        float gh = bhh[l];
        #pragma unroll
        for (int k = 0; k < 32; ++k) gh += WhhT[k * 96 + l] * hx[k];
        float gi2 = 0.f, gh2 = 0.f;
        if (l < 32) {
            gi2 = bih[64 + l];
            #pragma unroll
            for (int k = 0; k < 9; ++k) gi2 += WihT[k * 96 + 64 + l] * dyn[k];
            gh2 = bhh[64 + l];
            #pragma unroll
            for (int k = 0; k < 32; ++k) gh2 += WhhT[k * 96 + 64 + l] * hx[k];
        }
        gsum[l] = gi + gh;
        if (l < 32) { gin[l] = gi2; ghn[l] = gh2; }
        __syncthreads();

        float hnew = 0.f;
        if (l < 32) {
            const float r = 1.0f / (1.0f + expf(-gsum[l]));
            const float z = 1.0f / (1.0f + expf(-gsum[32 + l]));
            const float n = tanhf(gin[l] + r * ghn[l]);
            hnew = (1.0f - z) * n + z * hx[l];
        }
        __syncthreads();
        if (l < 32) hx[l] = hnew;
        __syncthreads();

        // ---- Stage C: h1 = leaky_relu(sta1 + W1[:, :32] @ hx) ----
        {
            float a = sta1[l];
            #pragma unroll
            for (int k = 0; k < 32; ++k) a += W1aT[k * 64 + l] * hx[k];
            h1[l] = (a >= 0.f) ? a : 0.01f * a;
        }
        __syncthreads();

        // ---- Stage D: h2 = leaky_relu(b2 + W2 @ h1) ----
        if (l < 32) {
            float a = b2s[l];
            #pragma unroll
            for (int k = 0; k < 64; ++k) a += W2T[k * 32 + l] * h1[k];
            h2[l] = (a >= 0.f) ? a : 0.01f * a;
        }
        __syncthreads();

        // ---- Stage E: pred = b3 + W3 @ h2 ----
        if (l < 6) {
            float a = b3s[l];
            #pragma unroll
            for (int k = 0; k < 32; ++k) a += W3s[l * 32 + k] * h2[k];
            predv[l] = a;
        }
        __syncthreads();

        // ---- Stage F: softclip covariance + Verlet update (scalar, lane 0) ----
        if (l == 0) {
            float s00 = predv[2] + 1e-8f, s01 = predv[3];
            float s10 = predv[4],          s11 = predv[5] + 1e-8f;
            const float nrm = sqrtf(s00 * s00 + s01 * s01 + s10 * s10 + s11 * s11);
            const float a1 = nrm / 5.0f;
            const float m  = fmaxf(a1, 1.0f);
            const float denom = m + logf(expf(a1 - m) + expf(1.0f - m));
            const float inv = 1.0f / denom;
            s00 *= inv; s01 *= inv; s10 *= inv; s11 *= inv;
            // sig = S @ S^T (symmetric)
            const float sig00 = s00 * s00 + s01 * s01;
            const float sig01 = s00 * s10 + s01 * s11;  // == sig10
            const float sig11 = s10 * s10 + s11 * s11;
            const float n0 = noise[((size_t)b * TFUT + ts) * 2 + 0];
            const float n1 = noise[((size_t)b * TFUT + ts) * 2 + 1];
            // xdotdot[j] = mu[j] + noise[j] * sum_i sig[i][j]
            const float xd0 = predv[0] + n0 * (sig00 + sig01);
            const float xd1 = predv[1] + n1 * (sig01 + sig11);
            const float nx0 = 2.0f * win[4] - win[2] + xd0;
            const float nx1 = 2.0f * win[5] - win[3] + xd1;
            out[((size_t)b * TFUT + ts) * 2 + 0] = nx0;
            out[((size_t)b * TFUT + ts) * 2 + 1] = nx1;
            win[0] = win[2]; win[1] = win[3];
            win[2] = win[4]; win[3] = win[5];
            win[4] = nx0;    win[5] = nx1;
        }
        __syncthreads();
    }
}

// ---------------------------------------------------------------------------
extern "C" void kernel_launch(void* const* d_in, const int* in_sizes, int n_in,
                              void* d_out, int out_size, void* d_ws, size_t ws_size,
                              hipStream_t stream) {
    const float* feat      = (const float*)d_in[0];
    const float* pred_map  = (const float*)d_in[1];
    const float* noise     = (const float*)d_in[2];
    const float* traj_past = (const float*)d_in[3];
    const float* W_ih      = (const float*)d_in[4];
    const float* W_hh      = (const float*)d_in[5];
    const float* b_ih      = (const float*)d_in[6];
    const float* b_hh      = (const float*)d_in[7];
    const float* past_W    = (const float*)d_in[8];
    const float* past_b    = (const float*)d_in[9];
    const float* W1        = (const float*)d_in[10];
    const float* b1        = (const float*)d_in[11];
    const float* W2        = (const float*)d_in[12];
    const float* b2        = (const float*)d_in[13];
    const float* W3        = (const float*)d_in[14];
    const float* b3        = (const float*)d_in[15];
    float* outp = (float*)d_out;
    float* sta1 = (float*)d_ws;  // 192*64 f32 = 48 KB scratch

    k_static<<<dim3(NB), dim3(1024), 0, stream>>>(feat, traj_past, past_W, past_b, W1, b1, sta1);
    k_recur<<<dim3(NB), dim3(64), 0, stream>>>(pred_map, noise, traj_past,
                                               W_ih, W_hh, b_ih, b_hh,
                                               W1, W2, b2, W3, b3, sta1, outp);
}

// Round 2
// 77.409 us; speedup vs baseline: 1.3529x; 1.3529x over previous
//
#include <hip/hip_runtime.h>
#include <hip/hip_bf16.h>
#include <math.h>

// Problem constants (from setup_inputs)
#define NB    192   // batch
#define NC    32    // feat channels
#define TFUT  27
#define HDIM  32

// ---------------------------------------------------------------------------
// Kernel 1: per-batch static features
//   pooled[2048] = 8x8 maxpool of feat_map[b]  (C*8*8)
//   past_enc[32] = traj_past[b] @ past_W.T + past_b
//   sta1[b][64]  = b1 + W1[:, 32:2112] @ [pooled, past_enc]
// ---------------------------------------------------------------------------
__global__ __launch_bounds__(1024) void k_static(
    const float* __restrict__ feat,      // (192,32,64,64)
    const float* __restrict__ traj_past, // (192,3,2)
    const float* __restrict__ past_W,    // (32,6)
    const float* __restrict__ past_b,    // (32)
    const float* __restrict__ W1,        // (64,2112)
    const float* __restrict__ b1,        // (64)
    float* __restrict__ sta1)            // (192,64)
{
    __shared__ __align__(16) float sta[2080];
    const int b = blockIdx.x;
    const int t = threadIdx.x;

    // Phase 1: maxpool. 1024 threads = 16 channels x 64 cells per iter, 2 iters.
    for (int it = 0; it < 2; ++it) {
        const int c    = it * 16 + (t >> 6);
        const int cell = t & 63;
        const int zi = cell >> 3, xi = cell & 7;
        const float* p = feat + ((size_t)b * NC + c) * 4096 + zi * 8 * 64 + xi * 8;
        float m = -3.402823466e38f;
        #pragma unroll
        for (int dz = 0; dz < 8; ++dz) {
            const float4 v0 = *reinterpret_cast<const float4*>(p + dz * 64);
            const float4 v1 = *reinterpret_cast<const float4*>(p + dz * 64 + 4);
            m = fmaxf(m, fmaxf(fmaxf(fmaxf(v0.x, v0.y), fmaxf(v0.z, v0.w)),
                               fmaxf(fmaxf(v1.x, v1.y), fmaxf(v1.z, v1.w))));
        }
        sta[c * 64 + cell] = m;
    }
    // Phase 2: past encoder
    if (t < 32) {
        float acc = past_b[t];
        #pragma unroll
        for (int k = 0; k < 6; ++k) acc += past_W[t * 6 + k] * traj_past[b * 6 + k];
        sta[2048 + t] = acc;
    }
    __syncthreads();

    // Phase 3: sta1[o] = b1[o] + sum_k W1[o][32+k]*sta[k]
    const int o = t >> 4, l = t & 15;
    const float* wrow = W1 + (size_t)o * 2112 + 32;
    float acc = 0.f;
    #pragma unroll 4
    for (int j = 0; j < 32; ++j) {
        const int k = j * 64 + l * 4;
        const float4 w = *reinterpret_cast<const float4*>(wrow + k);
        const float4 s = *reinterpret_cast<const float4*>(&sta[k]);
        acc += w.x * s.x + w.y * s.y + w.z * s.z + w.w * s.w;
    }
    if (l < 8) {  // remainder cols 2080..2111
        const int k = 2048 + l * 4;
        const float4 w = *reinterpret_cast<const float4*>(wrow + k);
        const float4 s = *reinterpret_cast<const float4*>(&sta[k]);
        acc += w.x * s.x + w.y * s.y + w.z * s.z + w.w * s.w;
    }
    acc += __shfl_xor(acc, 1);
    acc += __shfl_xor(acc, 2);
    acc += __shfl_xor(acc, 4);
    acc += __shfl_xor(acc, 8);
    if (l == 0) sta1[b * 64 + o] = b1[o] + acc;
}

// ---------------------------------------------------------------------------
// Kernel 2: recurrent loop, one wave per batch element, ALL state in registers.
// No __syncthreads in the loop; cross-lane via shfl/bpermute only.
// Lane assignment:
//   GRU rows: lane l -> row l (r-gate l<32, z-gate l>=32); lane l<32 -> row 64+l (n).
//   h1: lane l -> h1[l].   h2: lane l does row (l&31), cols (l>>5)*32..+31.
//   W3: lane l holds column (l&31) of all 6 rows; butterfly-reduced.
// ---------------------------------------------------------------------------
__global__ __launch_bounds__(64, 1) void k_recur(
    const float* __restrict__ pred_map,  // (192,1,64,64)
    const float* __restrict__ noise,     // (192,27,2)
    const float* __restrict__ traj_past, // (192,3,2)
    const float* __restrict__ W_ih,      // (96,9)
    const float* __restrict__ W_hh,      // (96,32)
    const float* __restrict__ b_ih,      // (96)
    const float* __restrict__ b_hh,      // (96)
    const float* __restrict__ W1,        // (64,2112), cols 0..31 used
    const float* __restrict__ W2,        // (32,64)
    const float* __restrict__ b2,        // (32)
    const float* __restrict__ W3,        // (6,32)
    const float* __restrict__ b3,        // (6)
    const float* __restrict__ sta1g,     // (192,64)
    float* __restrict__ out)             // (192,27,2)
{
    __shared__ __align__(16) float pm[4096];
    __shared__ __align__(8)  float nz[64];   // 54 used

    const int b = blockIdx.x;
    const int l = threadIdx.x;

    // ---- stage pred_map + noise into LDS ----
    {
        const float4* src = reinterpret_cast<const float4*>(pred_map + (size_t)b * 4096);
        float4* dst = reinterpret_cast<float4*>(pm);
        #pragma unroll
        for (int i = 0; i < 16; ++i) dst[l + i * 64] = src[l + i * 64];
    }
    if (l < TFUT * 2) nz[l] = noise[b * (TFUT * 2) + l];

    // ---- per-lane register weights ----
    float wih[9], wih2[9], whh[32], whh2[32], w1a[32], w2h[32], w3r[6];
    #pragma unroll
    for (int k = 0; k < 9; ++k)  wih[k] = W_ih[l * 9 + k];
    {
        const float4* p4 = reinterpret_cast<const float4*>(W_hh + l * 32);
        #pragma unroll
        for (int j = 0; j < 8; ++j) {
            const float4 v = p4[j];
            whh[4*j] = v.x; whh[4*j+1] = v.y; whh[4*j+2] = v.z; whh[4*j+3] = v.w;
        }
    }
    #pragma unroll
    for (int k = 0; k < 9; ++k)  wih2[k] = 0.f;
    #pragma unroll
    for (int k = 0; k < 32; ++k) whh2[k] = 0.f;
    float bihl = b_ih[l], bhhl = b_hh[l];
    float bih2 = 0.f, bhh2 = 0.f;
    if (l < 32) {
        #pragma unroll
        for (int k = 0; k < 9; ++k) wih2[k] = W_ih[(64 + l) * 9 + k];
        const float4* p4 = reinterpret_cast<const float4*>(W_hh + (64 + l) * 32);
        #pragma unroll
        for (int j = 0; j < 8; ++j) {
            const float4 v = p4[j];
            whh2[4*j] = v.x; whh2[4*j+1] = v.y; whh2[4*j+2] = v.z; whh2[4*j+3] = v.w;
        }
        bih2 = b_ih[64 + l]; bhh2 = b_hh[64 + l];
    }
    {
        const float4* p4 = reinterpret_cast<const float4*>(W1 + (size_t)l * 2112);
        #pragma unroll
        for (int j = 0; j < 8; ++j) {
            const float4 v = p4[j];
            w1a[4*j] = v.x; w1a[4*j+1] = v.y; w1a[4*j+2] = v.z; w1a[4*j+3] = v.w;
        }
    }
    {
        const int colbase = (l >> 5) * 32;
        const float4* p4 = reinterpret_cast<const float4*>(W2 + (l & 31) * 64 + colbase);
        #pragma unroll
        for (int j = 0; j < 8; ++j) {
            const float4 v = p4[j];
            w2h[4*j] = v.x; w2h[4*j+1] = v.y; w2h[4*j+2] = v.z; w2h[4*j+3] = v.w;
        }
    }
    #pragma unroll
    for (int r = 0; r < 6; ++r) w3r[r] = W3[r * 32 + (l & 31)];
    float b2l = b2[l & 31];
    float b3r[6];
    #pragma unroll
    for (int r = 0; r < 6; ++r) b3r[r] = b3[r];
    const float sta1l = sta1g[b * 64 + l];

    // replicated window, distributed hidden state
    float w[6];
    #pragma unroll
    for (int j = 0; j < 6; ++j) w[j] = traj_past[b * 6 + j];
    float hxloc = 0.f;
    float hxbc[32];
    #pragma unroll
    for (int k = 0; k < 32; ++k) hxbc[k] = 0.f;

    __syncthreads();

    const int colbase = (l >> 5) * 32;

    for (int ts = 0; ts < TFUT; ++ts) {
        const float2 nn = *reinterpret_cast<const float2*>(&nz[2 * ts]);

        // ---- bilinear sample (replicated in all lanes; LDS broadcast reads) ----
        float dyn[9];
        #pragma unroll
        for (int j = 0; j < 3; ++j) {
            float x = (w[2*j]   + 16.0f) * 2.0f - 0.5f;
            float z = (w[2*j+1] + 16.0f) * 2.0f - 0.5f;
            x = fminf(fmaxf(x, 0.0f), 63.0f);
            z = fminf(fmaxf(z, 0.0f), 63.0f);
            const float xf = floorf(x), zf = floorf(z);
            const int x0 = (int)xf, z0 = (int)zf;
            const int x1 = min(x0 + 1, 63), z1 = min(z0 + 1, 63);
            const float wx = x - xf, wz = z - zf;
            const float v00 = pm[z0 * 64 + x0], v01 = pm[z0 * 64 + x1];
            const float v10 = pm[z1 * 64 + x0], v11 = pm[z1 * 64 + x1];
            dyn[j] = v00 * (1.f - wx) * (1.f - wz) + v01 * wx * (1.f - wz)
                   + v10 * (1.f - wx) * wz        + v11 * wx * wz;
        }
        #pragma unroll
        for (int j = 0; j < 6; ++j) dyn[3 + j] = w[j];

        // ---- GRU gates (rows l and 64+l), pure register math ----
        float gi = bihl;
        #pragma unroll
        for (int k = 0; k < 9; ++k) gi += wih[k] * dyn[k];
        float a0 = 0.f, a1 = 0.f, a2 = 0.f, a3 = 0.f;
        #pragma unroll
        for (int k = 0; k < 32; k += 4) {
            a0 += whh[k]   * hxbc[k];
            a1 += whh[k+1] * hxbc[k+1];
            a2 += whh[k+2] * hxbc[k+2];
            a3 += whh[k+3] * hxbc[k+3];
        }
        const float gs = gi + bhhl + ((a0 + a1) + (a2 + a3));

        float gi2 = bih2;
        #pragma unroll
        for (int k = 0; k < 9; ++k) gi2 += wih2[k] * dyn[k];
        float c0 = 0.f, c1 = 0.f, c2 = 0.f, c3 = 0.f;
        #pragma unroll
        for (int k = 0; k < 32; k += 4) {
            c0 += whh2[k]   * hxbc[k];
            c1 += whh2[k+1] * hxbc[k+1];
            c2 += whh2[k+2] * hxbc[k+2];
            c3 += whh2[k+3] * hxbc[k+3];
        }
        const float gh2 = bhh2 + ((c0 + c1) + (c2 + c3));

        const float sg = 1.0f / (1.0f + expf(-gs));      // r on l<32, z on l>=32
        const float zval = __shfl_xor(sg, 32, 64);        // z for lanes l<32
        const float nval = tanhf(gi2 + sg * gh2);         // valid l<32
        const float hnew = (1.0f - zval) * nval + zval * hxloc;
        if (l < 32) hxloc = hnew;

        // ---- broadcast new hx (32 cross-lane reads) ----
        #pragma unroll
        for (int k = 0; k < 32; ++k) hxbc[k] = __shfl(hxloc, k, 64);

        // ---- h1[l] = leaky(sta1[l] + W1[l,:32] @ hx) ----
        float d0 = 0.f, d1 = 0.f, d2 = 0.f, d3 = 0.f;
        #pragma unroll
        for (int k = 0; k < 32; k += 4) {
            d0 += w1a[k]   * hxbc[k];
            d1 += w1a[k+1] * hxbc[k+1];
            d2 += w1a[k+2] * hxbc[k+2];
            d3 += w1a[k+3] * hxbc[k+3];
        }
        const float h1a = sta1l + ((d0 + d1) + (d2 + d3));
        const float h1l = (h1a >= 0.f) ? h1a : 0.01f * h1a;

        // ---- h2 split-dot: lane l does row (l&31), cols colbase..colbase+31 ----
        float p0 = 0.f, p1 = 0.f, p2 = 0.f, p3 = 0.f;
        #pragma unroll
        for (int j = 0; j < 32; j += 4) {
            const float t0 = __shfl(h1l, colbase + j,     64);
            const float t1 = __shfl(h1l, colbase + j + 1, 64);
            const float t2 = __shfl(h1l, colbase + j + 2, 64);
            const float t3 = __shfl(h1l, colbase + j + 3, 64);
            p0 += w2h[j]   * t0;
            p1 += w2h[j+1] * t1;
            p2 += w2h[j+2] * t2;
            p3 += w2h[j+3] * t3;
        }
        float p = ((p0 + p1) + (p2 + p3));
        p += __shfl_xor(p, 32, 64);                       // combine halves
        const float h2a = b2l + p;
        const float h2l = (h2a >= 0.f) ? h2a : 0.01f * h2a; // h2[l&31], replicated pairs

        // ---- pred = b3 + W3 @ h2 : 6 butterfly reductions over 32 lanes ----
        float pv[6];
        #pragma unroll
        for (int r = 0; r < 6; ++r) {
            float t = w3r[r] * h2l;
            t += __shfl_xor(t, 1,  64);
            t += __shfl_xor(t, 2,  64);
            t += __shfl_xor(t, 4,  64);
            t += __shfl_xor(t, 8,  64);
            t += __shfl_xor(t, 16, 64);
            pv[r] = t + b3r[r];
        }

        // ---- softclip covariance + Verlet (replicated in all lanes) ----
        float s00 = pv[2] + 1e-8f, s01 = pv[3];
        float s10 = pv[4],          s11 = pv[5] + 1e-8f;
        const float nrm = sqrtf(s00 * s00 + s01 * s01 + s10 * s10 + s11 * s11);
        const float arg = nrm * 0.2f;
        const float m   = fmaxf(arg, 1.0f);
        const float denom = m + logf(expf(arg - m) + expf(1.0f - m));
        const float inv = 1.0f / denom;
        s00 *= inv; s01 *= inv; s10 *= inv; s11 *= inv;
        const float sig00 = s00 * s00 + s01 * s01;
        const float sig01 = s00 * s10 + s01 * s11;        // == sig10
        const float sig11 = s10 * s10 + s11 * s11;
        const float xd0 = pv[0] + nn.x * (sig00 + sig01);
        const float xd1 = pv[1] + nn.y * (sig01 + sig11);
        const float nx0 = 2.0f * w[4] - w[2] + xd0;
        const float nx1 = 2.0f * w[5] - w[3] + xd1;
        if (l == 0) {
            float2 o; o.x = nx0; o.y = nx1;
            *reinterpret_cast<float2*>(out + ((size_t)b * TFUT + ts) * 2) = o;
        }
        w[0] = w[2]; w[1] = w[3];
        w[2] = w[4]; w[3] = w[5];
        w[4] = nx0;  w[5] = nx1;
    }
}

// ---------------------------------------------------------------------------
extern "C" void kernel_launch(void* const* d_in, const int* in_sizes, int n_in,
                              void* d_out, int out_size, void* d_ws, size_t ws_size,
                              hipStream_t stream) {
    const float* feat      = (const float*)d_in[0];
    const float* pred_map  = (const float*)d_in[1];
    const float* noise     = (const float*)d_in[2];
    const float* traj_past = (const float*)d_in[3];
    const float* W_ih      = (const float*)d_in[4];
    const float* W_hh      = (const float*)d_in[5];
    const float* b_ih      = (const float*)d_in[6];
    const float* b_hh      = (const float*)d_in[7];
    const float* past_W    = (const float*)d_in[8];
    const float* past_b    = (const float*)d_in[9];
    const float* W1        = (const float*)d_in[10];
    const float* b1        = (const float*)d_in[11];
    const float* W2        = (const float*)d_in[12];
    const float* b2        = (const float*)d_in[13];
    const float* W3        = (const float*)d_in[14];
    const float* b3        = (const float*)d_in[15];
    float* outp = (float*)d_out;
    float* sta1 = (float*)d_ws;  // 192*64 f32 scratch

    k_static<<<dim3(NB), dim3(1024), 0, stream>>>(feat, traj_past, past_W, past_b, W1, b1, sta1);
    k_recur<<<dim3(NB), dim3(64), 0, stream>>>(pred_map, noise, traj_past,
                                               W_ih, W_hh, b_ih, b_hh,
                                               W1, W2, b2, W3, b3, sta1, outp);
}

// Round 4
// 49.702 us; speedup vs baseline: 2.1071x; 1.5575x over previous
//
#include <hip/hip_runtime.h>
#include <hip/hip_bf16.h>
#include <math.h>

typedef unsigned int u32;
typedef __fp16 f16x2 __attribute__((ext_vector_type(2)));

#define NB    192
#define NC    32
#define TFUT  27

// ---- fast scalar helpers (availability-guarded) ----
#if __has_builtin(__builtin_amdgcn_rcpf)
#define RCPF(x) __builtin_amdgcn_rcpf(x)
#else
#define RCPF(x) (1.0f / (x))
#endif
#if __has_builtin(__builtin_amdgcn_sqrtf)
#define SQRTF(x) __builtin_amdgcn_sqrtf(x)
#else
#define SQRTF(x) sqrtf(x)
#endif
#if __has_builtin(__builtin_amdgcn_exp2f)
#define EXP2F(x) __builtin_amdgcn_exp2f(x)
#else
#define EXP2F(x) exp2f(x)
#endif
#if __has_builtin(__builtin_amdgcn_logf)
#define LOG2F(x) __builtin_amdgcn_logf(x)
#else
#define LOG2F(x) log2f(x)
#endif

__device__ __forceinline__ u32 pk16(float lo, float hi) {
    auto v = __builtin_amdgcn_cvt_pkrtz(lo, hi);
    return __builtin_bit_cast(u32, v);
}
__device__ __forceinline__ float fdot2pk(u32 a, u32 b, float c) {
#if __has_builtin(__builtin_amdgcn_fdot2)
    return __builtin_amdgcn_fdot2(__builtin_bit_cast(f16x2, a),
                                  __builtin_bit_cast(f16x2, b), c, false);
#else
    f16x2 av = __builtin_bit_cast(f16x2, a), bv = __builtin_bit_cast(f16x2, b);
    return c + (float)av[0] * (float)bv[0] + (float)av[1] * (float)bv[1];
#endif
}
__device__ __forceinline__ float swz_xor1(float v) {   // lane l <- lane l^1
    return __int_as_float(__builtin_amdgcn_ds_swizzle(__float_as_int(v), 0x041F));
}
__device__ __forceinline__ u32 rdl(u32 v, int lane) {
    return (u32)__builtin_amdgcn_readlane((int)v, lane);
}
__device__ __forceinline__ float rdlf(float v, int lane) {
    return __int_as_float(__builtin_amdgcn_readlane(__float_as_int(v), lane));
}
__device__ __forceinline__ float sigmoid_f(float x) {
    return RCPF(1.0f + EXP2F(-1.4426950408889634f * x));
}
__device__ __forceinline__ float tanh_f(float x) {     // 2*sigmoid(2x)-1
    return __builtin_fmaf(2.0f, RCPF(1.0f + EXP2F(-2.8853900817779268f * x)), -1.0f);
}

// ---------------------------------------------------------------------------
// Kernel 1: per-batch static features
// ---------------------------------------------------------------------------
__global__ __launch_bounds__(1024) void k_static(
    const float* __restrict__ feat,      // (192,32,64,64)
    const float* __restrict__ traj_past, // (192,3,2)
    const float* __restrict__ past_W,    // (32,6)
    const float* __restrict__ past_b,    // (32)
    const float* __restrict__ W1,        // (64,2112)
    const float* __restrict__ b1,        // (64)
    float* __restrict__ sta1)            // (192,64)
{
    __shared__ __align__(16) float sta[2080];
    const int b = blockIdx.x;
    const int t = threadIdx.x;

    for (int it = 0; it < 2; ++it) {
        const int c    = it * 16 + (t >> 6);
        const int cell = t & 63;
        const int zi = cell >> 3, xi = cell & 7;
        const float* p = feat + ((size_t)b * NC + c) * 4096 + zi * 8 * 64 + xi * 8;
        float m = -3.402823466e38f;
        #pragma unroll
        for (int dz = 0; dz < 8; ++dz) {
            const float4 v0 = *reinterpret_cast<const float4*>(p + dz * 64);
            const float4 v1 = *reinterpret_cast<const float4*>(p + dz * 64 + 4);
            m = fmaxf(m, fmaxf(fmaxf(fmaxf(v0.x, v0.y), fmaxf(v0.z, v0.w)),
                               fmaxf(fmaxf(v1.x, v1.y), fmaxf(v1.z, v1.w))));
        }
        sta[c * 64 + cell] = m;
    }
    if (t < 32) {
        float acc = past_b[t];
        #pragma unroll
        for (int k = 0; k < 6; ++k) acc += past_W[t * 6 + k] * traj_past[b * 6 + k];
        sta[2048 + t] = acc;
    }
    __syncthreads();

    const int o = t >> 4, l = t & 15;
    const float* wrow = W1 + (size_t)o * 2112 + 32;
    float acc = 0.f;
    #pragma unroll 4
    for (int j = 0; j < 32; ++j) {
        const int k = j * 64 + l * 4;
        const float4 w = *reinterpret_cast<const float4*>(wrow + k);
        const float4 s = *reinterpret_cast<const float4*>(&sta[k]);
        acc += w.x * s.x + w.y * s.y + w.z * s.z + w.w * s.w;
    }
    if (l < 8) {
        const int k = 2048 + l * 4;
        const float4 w = *reinterpret_cast<const float4*>(wrow + k);
        const float4 s = *reinterpret_cast<const float4*>(&sta[k]);
        acc += w.x * s.x + w.y * s.y + w.z * s.z + w.w * s.w;
    }
    acc += __shfl_xor(acc, 1);
    acc += __shfl_xor(acc, 2);
    acc += __shfl_xor(acc, 4);
    acc += __shfl_xor(acc, 8);
    if (l == 0) sta1[b * 64 + o] = b1[o] + acc;
}

// ---------------------------------------------------------------------------
// Kernel 2: recurrent loop; one wave per batch; f16-packed resident weights,
// cross-lane via readlane->SGPR; one bilinear sample per step.
// ---------------------------------------------------------------------------
__global__ __launch_bounds__(64, 1) void k_recur(
    const float* __restrict__ pred_map,  // (192,1,64,64)
    const float* __restrict__ noise,     // (192,27,2)
    const float* __restrict__ traj_past, // (192,3,2)
    const float* __restrict__ W_ih,      // (96,9)
    const float* __restrict__ W_hh,      // (96,32)
    const float* __restrict__ b_ih,      // (96)
    const float* __restrict__ b_hh,      // (96)
    const float* __restrict__ W1,        // (64,2112), cols 0..31 used
    const float* __restrict__ W2,        // (32,64)
    const float* __restrict__ b2,        // (32)
    const float* __restrict__ W3,        // (6,32)
    const float* __restrict__ b3,        // (6)
    const float* __restrict__ sta1g,     // (192,64)
    float* __restrict__ out)             // (192,27,2)
{
    __shared__ __align__(16) float pm[4096];
    __shared__ __align__(8)  float nz[56];

    const int b = blockIdx.x;
    const int l = threadIdx.x;
    const int m = l & 31;

    // ---- stage pred_map + noise into LDS ----
    {
        const float4* src = reinterpret_cast<const float4*>(pred_map + (size_t)b * 4096);
        float4* dst = reinterpret_cast<float4*>(pm);
        #pragma unroll
        for (int i = 0; i < 16; ++i) dst[l + i * 64] = src[l + i * 64];
    }
    if (l < TFUT * 2) nz[l] = noise[b * (TFUT * 2) + l];

    // ---- per-lane weights: f32 for the small GRU-input mats, f16x2 packed else ----
    float wih[9], wih2[9];
    #pragma unroll
    for (int k = 0; k < 9; ++k) {
        wih[k]  = W_ih[l * 9 + k];
        wih2[k] = W_ih[(64 + m) * 9 + k];
    }
    u32 whhp[16], whh2p[16], w1ap[16], w2p[32], w3p[16];
    #pragma unroll
    for (int j = 0; j < 16; ++j)
        whhp[j]  = pk16(W_hh[l * 32 + 2*j],        W_hh[l * 32 + 2*j + 1]);
    #pragma unroll
    for (int j = 0; j < 16; ++j)
        whh2p[j] = pk16(W_hh[(64 + m) * 32 + 2*j], W_hh[(64 + m) * 32 + 2*j + 1]);
    #pragma unroll
    for (int j = 0; j < 16; ++j)
        w1ap[j]  = pk16(W1[(size_t)l * 2112 + 2*j], W1[(size_t)l * 2112 + 2*j + 1]);
    #pragma unroll
    for (int j = 0; j < 32; ++j)
        w2p[j]   = pk16(W2[m * 64 + 2*j],          W2[m * 64 + 2*j + 1]);
    const int wr = (l < 6) ? l : 0;
    #pragma unroll
    for (int j = 0; j < 16; ++j)
        w3p[j]   = pk16(W3[wr * 32 + 2*j],         W3[wr * 32 + 2*j + 1]);

    const float bihl = b_ih[l], bhhl = b_hh[l];
    const float bih2 = b_ih[64 + m], bhh2 = b_hh[64 + m];
    const float b2l  = b2[m];
    float b3r[6];
    #pragma unroll
    for (int r = 0; r < 6; ++r) b3r[r] = b3[r];
    const float sta1l = sta1g[b * 64 + l];

    float w[6];
    #pragma unroll
    for (int j = 0; j < 6; ++j) w[j] = traj_past[b * 6 + j];
    float hxloc = 0.f;
    u32 hxpk[16];
    #pragma unroll
    for (int j = 0; j < 16; ++j) hxpk[j] = 0u;

    __syncthreads();

    // initial window samples (carried forward; only 1 new sample per step)
    auto bsample = [&](float px, float pz) -> float {
        float x = (px + 16.0f) * 2.0f - 0.5f;
        float z = (pz + 16.0f) * 2.0f - 0.5f;
        x = fminf(fmaxf(x, 0.0f), 63.0f);
        z = fminf(fmaxf(z, 0.0f), 63.0f);
        const float xf = floorf(x), zf = floorf(z);
        const int x0 = (int)xf, z0 = (int)zf;
        const int x1 = min(x0 + 1, 63), z1 = min(z0 + 1, 63);
        const float wx = x - xf, wz = z - zf;
        const float v00 = pm[z0 * 64 + x0], v01 = pm[z0 * 64 + x1];
        const float v10 = pm[z1 * 64 + x0], v11 = pm[z1 * 64 + x1];
        return v00 * (1.f - wx) * (1.f - wz) + v01 * wx * (1.f - wz)
             + v10 * (1.f - wx) * wz        + v11 * wx * wz;
    };
    float s0 = bsample(w[0], w[1]);
    float s1 = bsample(w[2], w[3]);
    float s2 = bsample(w[4], w[5]);

    const bool odd = (l & 1);

    for (int ts = 0; ts < TFUT; ++ts) {
        const float2 nn = *reinterpret_cast<const float2*>(&nz[2 * ts]);

        // ---- GRU: gi (f32, 9 terms) + gh (f16-packed, 16 dot2) ----
        float gi = bihl + wih[0] * s0 + wih[1] * s1 + wih[2] * s2;
        #pragma unroll
        for (int j = 0; j < 6; ++j) gi += wih[3 + j] * w[j];
        float gi2 = bih2 + wih2[0] * s0 + wih2[1] * s1 + wih2[2] * s2;
        #pragma unroll
        for (int j = 0; j < 6; ++j) gi2 += wih2[3 + j] * w[j];

        float A0 = 0.f, A1 = 0.f, A2 = 0.f, A3 = 0.f;
        float C0 = 0.f, C1 = 0.f, C2 = 0.f, C3 = 0.f;
        #pragma unroll
        for (int j = 0; j < 16; j += 4) {
            A0 = fdot2pk(hxpk[j],   whhp[j],   A0);
            A1 = fdot2pk(hxpk[j+1], whhp[j+1], A1);
            A2 = fdot2pk(hxpk[j+2], whhp[j+2], A2);
            A3 = fdot2pk(hxpk[j+3], whhp[j+3], A3);
            C0 = fdot2pk(hxpk[j],   whh2p[j],   C0);
            C1 = fdot2pk(hxpk[j+1], whh2p[j+1], C1);
            C2 = fdot2pk(hxpk[j+2], whh2p[j+2], C2);
            C3 = fdot2pk(hxpk[j+3], whh2p[j+3], C3);
        }
        const float gs  = gi  + bhhl + ((A0 + A1) + (A2 + A3));
        const float gh2 = bhh2 + ((C0 + C1) + (C2 + C3));

        const float sg = sigmoid_f(gs);            // r on l<32, z on l>=32
        const float zv = __shfl_xor(sg, 32, 64);   // z for lanes<32
        const float nv = tanh_f(gi2 + sg * gh2);
        const float hnew = (1.0f - zv) * nv + zv * hxloc;  // valid l<32
        hxloc = hnew;

        // ---- replicate hx as 16 packed SGPRs (swizzle-pack + readlane) ----
        {
            const float nb = swz_xor1(hnew);
            const float plo = odd ? nb : hnew;
            const float phi = odd ? hnew : nb;
            const u32 hpk = pk16(plo, phi);
            #pragma unroll
            for (int j = 0; j < 16; ++j) hxpk[j] = rdl(hpk, 2 * j);
        }

        // ---- h1[l] = leaky(sta1[l] + W1[l,:32] @ hx) ----
        float D0 = 0.f, D1 = 0.f, D2 = 0.f, D3 = 0.f;
        #pragma unroll
        for (int j = 0; j < 16; j += 4) {
            D0 = fdot2pk(hxpk[j],   w1ap[j],   D0);
            D1 = fdot2pk(hxpk[j+1], w1ap[j+1], D1);
            D2 = fdot2pk(hxpk[j+2], w1ap[j+2], D2);
            D3 = fdot2pk(hxpk[j+3], w1ap[j+3], D3);
        }
        const float h1a = sta1l + ((D0 + D1) + (D2 + D3));
        const float h1l = (h1a >= 0.f) ? h1a : 0.01f * h1a;

        // ---- replicate h1 as 32 packed SGPRs ----
        u32 h1pk[32];
        {
            const float nb = swz_xor1(h1l);
            const float plo = odd ? nb : h1l;
            const float phi = odd ? h1l : nb;
            const u32 hpk = pk16(plo, phi);
            #pragma unroll
            for (int j = 0; j < 32; ++j) h1pk[j] = rdl(hpk, 2 * j);
        }

        // ---- h2[m] = leaky(b2[m] + W2[m,:] @ h1) : full 64-col row per lane ----
        float P0 = 0.f, P1 = 0.f, P2 = 0.f, P3 = 0.f;
        #pragma unroll
        for (int j = 0; j < 32; j += 4) {
            P0 = fdot2pk(h1pk[j],   w2p[j],   P0);
            P1 = fdot2pk(h1pk[j+1], w2p[j+1], P1);
            P2 = fdot2pk(h1pk[j+2], w2p[j+2], P2);
            P3 = fdot2pk(h1pk[j+3], w2p[j+3], P3);
        }
        const float h2a = b2l + ((P0 + P1) + (P2 + P3));
        const float h2l = (h2a >= 0.f) ? h2a : 0.01f * h2a;  // h2[m]

        // ---- replicate h2 as 16 packed SGPRs; pv rows on lanes 0..5 ----
        u32 h2pk[16];
        {
            const float nb = swz_xor1(h2l);
            const float plo = odd ? nb : h2l;
            const float phi = odd ? h2l : nb;
            const u32 hpk = pk16(plo, phi);
            #pragma unroll
            for (int j = 0; j < 16; ++j) h2pk[j] = rdl(hpk, 2 * j);
        }
        float Q0 = 0.f, Q1 = 0.f, Q2 = 0.f, Q3 = 0.f;
        #pragma unroll
        for (int j = 0; j < 16; j += 4) {
            Q0 = fdot2pk(h2pk[j],   w3p[j],   Q0);
            Q1 = fdot2pk(h2pk[j+1], w3p[j+1], Q1);
            Q2 = fdot2pk(h2pk[j+2], w3p[j+2], Q2);
            Q3 = fdot2pk(h2pk[j+3], w3p[j+3], Q3);
        }
        const float praw = ((Q0 + Q1) + (Q2 + Q3));  // W3 row wr dot h2 (lanes 0..5)

        const float pv0 = rdlf(praw, 0) + b3r[0];
        const float pv1 = rdlf(praw, 1) + b3r[1];
        const float pv2 = rdlf(praw, 2) + b3r[2];
        const float pv3 = rdlf(praw, 3) + b3r[3];
        const float pv4 = rdlf(praw, 4) + b3r[4];
        const float pv5 = rdlf(praw, 5) + b3r[5];

        // ---- softclip covariance + Verlet (uniform, replicated) ----
        float s00 = pv2 + 1e-8f, s01 = pv3;
        float s10 = pv4,          s11 = pv5 + 1e-8f;
        const float nrm = SQRTF(s00 * s00 + s01 * s01 + s10 * s10 + s11 * s11);
        const float arg = nrm * 0.2f;
        const float mm  = fmaxf(arg, 1.0f);
        const float d   = fabsf(arg - 1.0f);
        const float denom = mm + 0.6931471805599453f *
                            LOG2F(1.0f + EXP2F(-1.4426950408889634f * d));
        const float inv = RCPF(denom);
        s00 *= inv; s01 *= inv; s10 *= inv; s11 *= inv;
        const float sig00 = s00 * s00 + s01 * s01;
        const float sig01 = s00 * s10 + s01 * s11;   // == sig10
        const float sig11 = s10 * s10 + s11 * s11;
        const float xd0 = pv0 + nn.x * (sig00 + sig01);
        const float xd1 = pv1 + nn.y * (sig01 + sig11);
        const float nx0 = 2.0f * w[4] - w[2] + xd0;
        const float nx1 = 2.0f * w[5] - w[3] + xd1;

        if (l == 0) {
            float2 o; o.x = nx0; o.y = nx1;
            *reinterpret_cast<float2*>(out + ((size_t)b * TFUT + ts) * 2) = o;
        }

        // window shift + carry samples; one new bilinear sample
        w[0] = w[2]; w[1] = w[3];
        w[2] = w[4]; w[3] = w[5];
        w[4] = nx0;  w[5] = nx1;
        s0 = s1; s1 = s2;
        s2 = bsample(nx0, nx1);
    }
}

// ---------------------------------------------------------------------------
extern "C" void kernel_launch(void* const* d_in, const int* in_sizes, int n_in,
                              void* d_out, int out_size, void* d_ws, size_t ws_size,
                              hipStream_t stream) {
    const float* feat      = (const float*)d_in[0];
    const float* pred_map  = (const float*)d_in[1];
    const float* noise     = (const float*)d_in[2];
    const float* traj_past = (const float*)d_in[3];
    const float* W_ih      = (const float*)d_in[4];
    const float* W_hh      = (const float*)d_in[5];
    const float* b_ih      = (const float*)d_in[6];
    const float* b_hh      = (const float*)d_in[7];
    const float* past_W    = (const float*)d_in[8];
    const float* past_b    = (const float*)d_in[9];
    const float* W1        = (const float*)d_in[10];
    const float* b1        = (const float*)d_in[11];
    const float* W2        = (const float*)d_in[12];
    const float* b2        = (const float*)d_in[13];
    const float* W3        = (const float*)d_in[14];
    const float* b3        = (const float*)d_in[15];
    float* outp = (float*)d_out;
    float* sta1 = (float*)d_ws;  // 192*64 f32 scratch

    k_static<<<dim3(NB), dim3(1024), 0, stream>>>(feat, traj_past, past_W, past_b, W1, b1, sta1);
    k_recur<<<dim3(NB), dim3(64), 0, stream>>>(pred_map, noise, traj_past,
                                               W_ih, W_hh, b_ih, b_hh,
                                               W1, W2, b2, W3, b3, sta1, outp);
}

// Round 5
// 47.179 us; speedup vs baseline: 2.2198x; 1.0535x over previous
//
#include <hip/hip_runtime.h>
#include <hip/hip_bf16.h>
#include <math.h>

typedef unsigned int u32;
typedef __fp16 f16x2 __attribute__((ext_vector_type(2)));
typedef u32 u32x4 __attribute__((ext_vector_type(4)));

#define NB    192
#define NC    32
#define TFUT  27
#define BLOB_F_OFF (NB * 64)   // float offset of packed-weight blob inside ws

// ---- fast scalar helpers (availability-guarded) ----
#if __has_builtin(__builtin_amdgcn_rcpf)
#define RCPF(x) __builtin_amdgcn_rcpf(x)
#else
#define RCPF(x) (1.0f / (x))
#endif
#if __has_builtin(__builtin_amdgcn_sqrtf)
#define SQRTF(x) __builtin_amdgcn_sqrtf(x)
#else
#define SQRTF(x) sqrtf(x)
#endif
#if __has_builtin(__builtin_amdgcn_exp2f)
#define EXP2F(x) __builtin_amdgcn_exp2f(x)
#else
#define EXP2F(x) exp2f(x)
#endif
#if __has_builtin(__builtin_amdgcn_logf)
#define LOG2F(x) __builtin_amdgcn_logf(x)
#else
#define LOG2F(x) log2f(x)
#endif

__device__ __forceinline__ u32 pk16(float lo, float hi) {
    auto v = __builtin_amdgcn_cvt_pkrtz(lo, hi);
    return __builtin_bit_cast(u32, v);
}
__device__ __forceinline__ float fdot2pk(u32 a, u32 b, float c) {
#if __has_builtin(__builtin_amdgcn_fdot2)
    return __builtin_amdgcn_fdot2(__builtin_bit_cast(f16x2, a),
                                  __builtin_bit_cast(f16x2, b), c, false);
#else
    f16x2 av = __builtin_bit_cast(f16x2, a), bv = __builtin_bit_cast(f16x2, b);
    return c + (float)av[0] * (float)bv[0] + (float)av[1] * (float)bv[1];
#endif
}
__device__ __forceinline__ u32 rdl(u32 v, int lane) {
    return (u32)__builtin_amdgcn_readlane((int)v, lane);
}
__device__ __forceinline__ float rdlf(float v, int lane) {
    return __int_as_float(__builtin_amdgcn_readlane(__float_as_int(v), lane));
}
// lane l <- lane l^1 via DPP quad_perm(1,0,3,2) — pure VALU, no LDS
__device__ __forceinline__ float dpp_xor1(float v) {
    return __int_as_float(__builtin_amdgcn_update_dpp(
        0, __float_as_int(v), 0xB1, 0xF, 0xF, true));
}
__device__ __forceinline__ float sigmoid_f(float x) {
    return RCPF(1.0f + EXP2F(-1.4426950408889634f * x));
}
__device__ __forceinline__ float tanh_f(float x) {
    return __builtin_fmaf(2.0f, RCPF(1.0f + EXP2F(-2.8853900817779268f * x)), -1.0f);
}

// ---------------------------------------------------------------------------
// Kernel 1: blocks 0..191: per-batch static features (maxpool + past_enc + sta1)
//           block 192: pack all per-lane recurrent weights into ws blob
// ---------------------------------------------------------------------------
__global__ __launch_bounds__(1024) void k_static(
    const float* __restrict__ feat,      // (192,32,64,64)
    const float* __restrict__ traj_past, // (192,3,2)
    const float* __restrict__ past_W,    // (32,6)
    const float* __restrict__ past_b,    // (32)
    const float* __restrict__ W1,        // (64,2112)
    const float* __restrict__ b1,        // (64)
    const float* __restrict__ W_ih,      // (96,9)
    const float* __restrict__ W_hh,      // (96,32)
    const float* __restrict__ b_ih,      // (96)
    const float* __restrict__ b_hh,      // (96)
    const float* __restrict__ W2,        // (32,64)
    const float* __restrict__ b2,        // (32)
    const float* __restrict__ W3,        // (6,32)
    const float* __restrict__ b3,        // (6)
    float* __restrict__ ws)              // [0..12287]=sta1, then blob
{
    const int b = blockIdx.x;
    const int t = threadIdx.x;

    if (b == NB) {
        // ---- weight-pack block: 64 lanes, one blob row per lane ----
        if (t >= 64) return;
        const int l = t, m2 = l & 31;
        u32* blob = reinterpret_cast<u32*>(ws) + BLOB_F_OFF + (size_t)l * 128;
        #pragma unroll
        for (int k = 0; k < 9; ++k) {
            blob[k]     = __float_as_uint(W_ih[l * 9 + k]);
            blob[9 + k] = __float_as_uint(W_ih[(64 + m2) * 9 + k]);
        }
        #pragma unroll
        for (int j = 0; j < 16; ++j) {
            blob[18 + j] = pk16(W_hh[l * 32 + 2*j],          W_hh[l * 32 + 2*j + 1]);
            blob[34 + j] = pk16(W_hh[(64 + m2) * 32 + 2*j],  W_hh[(64 + m2) * 32 + 2*j + 1]);
            blob[50 + j] = pk16(W1[(size_t)l * 2112 + 2*j],  W1[(size_t)l * 2112 + 2*j + 1]);
        }
        #pragma unroll
        for (int j = 0; j < 32; ++j)
            blob[66 + j] = pk16(W2[m2 * 64 + 2*j], W2[m2 * 64 + 2*j + 1]);
        const int wr = (l < 6) ? l : 0;
        #pragma unroll
        for (int j = 0; j < 16; ++j)
            blob[98 + j] = pk16(W3[wr * 32 + 2*j], W3[wr * 32 + 2*j + 1]);
        blob[114] = __float_as_uint(b_ih[l]);
        blob[115] = __float_as_uint(b_hh[l]);
        blob[116] = __float_as_uint(b_ih[64 + m2]);
        blob[117] = __float_as_uint(b_hh[64 + m2]);
        blob[118] = __float_as_uint(b2[m2]);
        #pragma unroll
        for (int r = 0; r < 6; ++r) blob[119 + r] = __float_as_uint(b3[r]);
        blob[125] = blob[126] = blob[127] = 0u;
        return;
    }

    __shared__ __align__(16) float sta[2080];

    for (int it = 0; it < 2; ++it) {
        const int c    = it * 16 + (t >> 6);
        const int cell = t & 63;
        const int zi = cell >> 3, xi = cell & 7;
        const float* p = feat + ((size_t)b * NC + c) * 4096 + zi * 8 * 64 + xi * 8;
        float m = -3.402823466e38f;
        #pragma unroll
        for (int dz = 0; dz < 8; ++dz) {
            const float4 v0 = *reinterpret_cast<const float4*>(p + dz * 64);
            const float4 v1 = *reinterpret_cast<const float4*>(p + dz * 64 + 4);
            m = fmaxf(m, fmaxf(fmaxf(fmaxf(v0.x, v0.y), fmaxf(v0.z, v0.w)),
                               fmaxf(fmaxf(v1.x, v1.y), fmaxf(v1.z, v1.w))));
        }
        sta[c * 64 + cell] = m;
    }
    if (t < 32) {
        float acc = past_b[t];
        #pragma unroll
        for (int k = 0; k < 6; ++k) acc += past_W[t * 6 + k] * traj_past[b * 6 + k];
        sta[2048 + t] = acc;
    }
    __syncthreads();

    const int o = t >> 4, l = t & 15;
    const float* wrow = W1 + (size_t)o * 2112 + 32;
    float acc = 0.f;
    #pragma unroll 4
    for (int j = 0; j < 32; ++j) {
        const int k = j * 64 + l * 4;
        const float4 w = *reinterpret_cast<const float4*>(wrow + k);
        const float4 s = *reinterpret_cast<const float4*>(&sta[k]);
        acc += w.x * s.x + w.y * s.y + w.z * s.z + w.w * s.w;
    }
    if (l < 8) {
        const int k = 2048 + l * 4;
        const float4 w = *reinterpret_cast<const float4*>(wrow + k);
        const float4 s = *reinterpret_cast<const float4*>(&sta[k]);
        acc += w.x * s.x + w.y * s.y + w.z * s.z + w.w * s.w;
    }
    acc += __shfl_xor(acc, 1);
    acc += __shfl_xor(acc, 2);
    acc += __shfl_xor(acc, 4);
    acc += __shfl_xor(acc, 8);
    if (l == 0) ws[b * 64 + o] = b1[o] + acc;
}

// ---------------------------------------------------------------------------
// Kernel 2: recurrence. One wave per batch; weights from coalesced blob;
// DPP-based broadcasts (no LDS swizzle); GRU hidden dots software-pipelined.
// ---------------------------------------------------------------------------
__global__ __launch_bounds__(64, 1) void k_recur(
    const float* __restrict__ pred_map,  // (192,1,64,64)
    const float* __restrict__ noise,     // (192,27,2)
    const float* __restrict__ traj_past, // (192,3,2)
    const float* __restrict__ ws,        // sta1 + blob
    float* __restrict__ out)             // (192,27,2)
{
    __shared__ __align__(16) float pm[4096];
    __shared__ __align__(8)  float nz[56];

    const int b = blockIdx.x;
    const int l = threadIdx.x;

    // ---- stage pred_map + noise into LDS ----
    {
        const float4* src = reinterpret_cast<const float4*>(pred_map + (size_t)b * 4096);
        float4* dst = reinterpret_cast<float4*>(pm);
        #pragma unroll
        for (int i = 0; i < 16; ++i) dst[l + i * 64] = src[l + i * 64];
    }
    if (l < TFUT * 2) nz[l] = noise[b * (TFUT * 2) + l];

    // ---- coalesced weight-blob load: 32 x dwordx4 per lane ----
    const u32* blob = reinterpret_cast<const u32*>(ws) + BLOB_F_OFF + (size_t)l * 128;
    u32x4 dv[32];
    #pragma unroll
    for (int j = 0; j < 32; ++j)
        dv[j] = reinterpret_cast<const u32x4*>(blob)[j];
#define DW(i) (dv[(i) >> 2][(i) & 3])
#define DF(i) __int_as_float((int)DW(i))

    const float sta1l = ws[b * 64 + l];

    float w[6];
    #pragma unroll
    for (int j = 0; j < 6; ++j) w[j] = traj_past[b * 6 + j];
    float hxloc = 0.f;
    u32 hxpk[16];
    #pragma unroll
    for (int j = 0; j < 16; ++j) hxpk[j] = 0u;
    float Adot = 0.f, Cdot = 0.f;   // carried W_hh·hx for r/z and n gates (hx0=0)

    __syncthreads();

    auto bsample = [&](float px, float pz) -> float {
        float x = (px + 16.0f) * 2.0f - 0.5f;
        float z = (pz + 16.0f) * 2.0f - 0.5f;
        x = fminf(fmaxf(x, 0.0f), 63.0f);
        z = fminf(fmaxf(z, 0.0f), 63.0f);
        const float xf = floorf(x), zf = floorf(z);
        const int x0 = (int)xf, z0 = (int)zf;
        const int x1 = min(x0 + 1, 63), z1 = min(z0 + 1, 63);
        const float wx = x - xf, wz = z - zf;
        const float v00 = pm[z0 * 64 + x0], v01 = pm[z0 * 64 + x1];
        const float v10 = pm[z1 * 64 + x0], v11 = pm[z1 * 64 + x1];
        return v00 * (1.f - wx) * (1.f - wz) + v01 * wx * (1.f - wz)
             + v10 * (1.f - wx) * wz        + v11 * wx * wz;
    };
    float s0 = bsample(w[0], w[1]);
    float s1 = bsample(w[2], w[3]);
    float s2 = bsample(w[4], w[5]);

    for (int ts = 0; ts < TFUT; ++ts) {
        const float2 nn = *reinterpret_cast<const float2*>(&nz[2 * ts]);

        // ---- gates: window terms first, fresh-sample terms last (hide LDS wait)
        float gi  = DF(114) + DF(3) * w[0] + DF(4) * w[1] + DF(5) * w[2]
                            + DF(6) * w[3] + DF(7) * w[4] + DF(8) * w[5];
        float gi2 = DF(116) + DF(12) * w[0] + DF(13) * w[1] + DF(14) * w[2]
                            + DF(15) * w[3] + DF(16) * w[4] + DF(17) * w[5];
        gi  += DF(0) * s0 + DF(1) * s1 + DF(2) * s2;
        gi2 += DF(9) * s0 + DF(10) * s1 + DF(11) * s2;

        const float gs   = gi + DF(115) + Adot;    // r (l<32) / z (l>=32)
        const float gh2v = DF(117) + Cdot;         // n-gate hidden part
        const float sg = sigmoid_f(gs);
        const float zv = __shfl_xor(sg, 32, 64);   // z for lanes<32
        const float nv = tanh_f(gi2 + sg * gh2v);
        const float hnew = (1.0f - zv) * nv + zv * hxloc;  // valid l<32
        hxloc = hnew;

        // ---- broadcast hx (DPP pair-pack + readlane of even lanes) ----
        const u32 hpk = pk16(hnew, dpp_xor1(hnew));
        #pragma unroll
        for (int j = 0; j < 16; ++j) hxpk[j] = rdl(hpk, 2 * j);

        // ---- NEXT-step GRU hidden dots (independent of the tail below) ----
        {
            float A0 = 0.f, A1 = 0.f, A2 = 0.f, A3 = 0.f;
            float C0 = 0.f, C1 = 0.f, C2 = 0.f, C3 = 0.f;
            #pragma unroll
            for (int j = 0; j < 16; j += 4) {
                A0 = fdot2pk(hxpk[j],   DW(18 + j),     A0);
                A1 = fdot2pk(hxpk[j+1], DW(18 + j + 1), A1);
                A2 = fdot2pk(hxpk[j+2], DW(18 + j + 2), A2);
                A3 = fdot2pk(hxpk[j+3], DW(18 + j + 3), A3);
                C0 = fdot2pk(hxpk[j],   DW(34 + j),     C0);
                C1 = fdot2pk(hxpk[j+1], DW(34 + j + 1), C1);
                C2 = fdot2pk(hxpk[j+2], DW(34 + j + 2), C2);
                C3 = fdot2pk(hxpk[j+3], DW(34 + j + 3), C3);
            }
            Adot = (A0 + A1) + (A2 + A3);
            Cdot = (C0 + C1) + (C2 + C3);
        }

        // ---- h1[l] = leaky(sta1[l] + W1[l,:32] @ hx) ----
        float D0 = 0.f, D1 = 0.f, D2 = 0.f, D3 = 0.f;
        #pragma unroll
        for (int j = 0; j < 16; j += 4) {
            D0 = fdot2pk(hxpk[j],   DW(50 + j),     D0);
            D1 = fdot2pk(hxpk[j+1], DW(50 + j + 1), D1);
            D2 = fdot2pk(hxpk[j+2], DW(50 + j + 2), D2);
            D3 = fdot2pk(hxpk[j+3], DW(50 + j + 3), D3);
        }
        const float h1a = sta1l + ((D0 + D1) + (D2 + D3));
        const float h1l = (h1a >= 0.f) ? h1a : 0.01f * h1a;

        // ---- broadcast h1 (32 pairs) ----
        const u32 h1p = pk16(h1l, dpp_xor1(h1l));
        u32 h1pk[32];
        #pragma unroll
        for (int j = 0; j < 32; ++j) h1pk[j] = rdl(h1p, 2 * j);

        // ---- h2[m] = leaky(b2[m] + W2[m,:] @ h1), 8 accumulators ----
        float P0 = 0.f, P1 = 0.f, P2 = 0.f, P3 = 0.f;
        float P4 = 0.f, P5 = 0.f, P6 = 0.f, P7 = 0.f;
        #pragma unroll
        for (int j = 0; j < 32; j += 8) {
            P0 = fdot2pk(h1pk[j],   DW(66 + j),     P0);
            P1 = fdot2pk(h1pk[j+1], DW(66 + j + 1), P1);
            P2 = fdot2pk(h1pk[j+2], DW(66 + j + 2), P2);
            P3 = fdot2pk(h1pk[j+3], DW(66 + j + 3), P3);
            P4 = fdot2pk(h1pk[j+4], DW(66 + j + 4), P4);
            P5 = fdot2pk(h1pk[j+5], DW(66 + j + 5), P5);
            P6 = fdot2pk(h1pk[j+6], DW(66 + j + 6), P6);
            P7 = fdot2pk(h1pk[j+7], DW(66 + j + 7), P7);
        }
        const float h2a = DF(118) + (((P0 + P1) + (P2 + P3)) + ((P4 + P5) + (P6 + P7)));
        const float h2l = (h2a >= 0.f) ? h2a : 0.01f * h2a;

        // ---- broadcast h2; W3 dots on all lanes (rows 0..5 meaningful) ----
        const u32 h2p = pk16(h2l, dpp_xor1(h2l));
        u32 h2pk[16];
        #pragma unroll
        for (int j = 0; j < 16; ++j) h2pk[j] = rdl(h2p, 2 * j);

        float Q0 = 0.f, Q1 = 0.f, Q2 = 0.f, Q3 = 0.f;
        #pragma unroll
        for (int j = 0; j < 16; j += 4) {
            Q0 = fdot2pk(h2pk[j],   DW(98 + j),     Q0);
            Q1 = fdot2pk(h2pk[j+1], DW(98 + j + 1), Q1);
            Q2 = fdot2pk(h2pk[j+2], DW(98 + j + 2), Q2);
            Q3 = fdot2pk(h2pk[j+3], DW(98 + j + 3), Q3);
        }
        const float praw = (Q0 + Q1) + (Q2 + Q3);

        const float pv0 = rdlf(praw, 0) + DF(119);
        const float pv1 = rdlf(praw, 1) + DF(120);
        const float pv2 = rdlf(praw, 2) + DF(121);
        const float pv3 = rdlf(praw, 3) + DF(122);
        const float pv4 = rdlf(praw, 4) + DF(123);
        const float pv5 = rdlf(praw, 5) + DF(124);

        // ---- softclip covariance + Verlet (uniform, replicated) ----
        float s00 = pv2 + 1e-8f, s01 = pv3;
        float s10 = pv4,          s11 = pv5 + 1e-8f;
        const float nrm = SQRTF(s00 * s00 + s01 * s01 + s10 * s10 + s11 * s11);
        const float arg = nrm * 0.2f;
        const float mm  = fmaxf(arg, 1.0f);
        const float dd  = fabsf(arg - 1.0f);
        const float denom = mm + 0.6931471805599453f *
                            LOG2F(1.0f + EXP2F(-1.4426950408889634f * dd));
        const float inv = RCPF(denom);
        s00 *= inv; s01 *= inv; s10 *= inv; s11 *= inv;
        const float sig00 = s00 * s00 + s01 * s01;
        const float sig01 = s00 * s10 + s01 * s11;   // == sig10
        const float sig11 = s10 * s10 + s11 * s11;
        const float xd0 = pv0 + nn.x * (sig00 + sig01);
        const float xd1 = pv1 + nn.y * (sig01 + sig11);
        const float nx0 = 2.0f * w[4] - w[2] + xd0;
        const float nx1 = 2.0f * w[5] - w[3] + xd1;

        if (l == 0) {
            float2 o; o.x = nx0; o.y = nx1;
            *reinterpret_cast<float2*>(out + ((size_t)b * TFUT + ts) * 2) = o;
        }

        w[0] = w[2]; w[1] = w[3];
        w[2] = w[4]; w[3] = w[5];
        w[4] = nx0;  w[5] = nx1;
        s0 = s1; s1 = s2;
        s2 = bsample(nx0, nx1);
    }
#undef DW
#undef DF
}

// ---------------------------------------------------------------------------
extern "C" void kernel_launch(void* const* d_in, const int* in_sizes, int n_in,
                              void* d_out, int out_size, void* d_ws, size_t ws_size,
                              hipStream_t stream) {
    const float* feat      = (const float*)d_in[0];
    const float* pred_map  = (const float*)d_in[1];
    const float* noise     = (const float*)d_in[2];
    const float* traj_past = (const float*)d_in[3];
    const float* W_ih      = (const float*)d_in[4];
    const float* W_hh      = (const float*)d_in[5];
    const float* b_ih      = (const float*)d_in[6];
    const float* b_hh      = (const float*)d_in[7];
    const float* past_W    = (const float*)d_in[8];
    const float* past_b    = (const float*)d_in[9];
    const float* W1        = (const float*)d_in[10];
    const float* b1        = (const float*)d_in[11];
    const float* W2        = (const float*)d_in[12];
    const float* b2        = (const float*)d_in[13];
    const float* W3        = (const float*)d_in[14];
    const float* b3        = (const float*)d_in[15];
    float* outp = (float*)d_out;
    float* ws   = (float*)d_ws;   // sta1 (48 KB) + weight blob (32 KB)

    k_static<<<dim3(NB + 1), dim3(1024), 0, stream>>>(
        feat, traj_past, past_W, past_b, W1, b1,
        W_ih, W_hh, b_ih, b_hh, W2, b2, W3, b3, ws);
    k_recur<<<dim3(NB), dim3(64), 0, stream>>>(pred_map, noise, traj_past, ws, outp);
}